// Round 5
// baseline (196.954 us; speedup 1.0000x reference)
//
#include <hip/hip_runtime.h>
#include <hip/hip_bf16.h>

// ConvSelfAttentionModule: B=4, C=256, CQK=128, N=4096 (64x64), fp32 in/out.
// R13 = R12 + software-pipelined k_fav. R4 counters: k_fav 62us, MfmaUtil 33%,
// VALU 26%, traffic ideal -> bound by the serial QK->exp->write->barrier->AV
// chain. New loop: exp/write of tile t overlaps QK MFMA of tile t+1 (they are
// independent); one lgkm-only barrier/iter; AV(t) after. QK operand order
// swapped (A=Q,B=K) so each lane holds 4 consecutive i at one j -> sE writes
// become 4 packed ds_write_b32 (was 16 ds_write_b16). sE dbuf WAR-safe:
// write(t+2) and read(t) of one buffer are separated by barrier(t+1).
//   k_wcvt   : W -> f16
//   k_xsplit : transpose x[b][c][n] -> xT[b][n][c] f16
//   k_proj   : f16 MFMA GEMM -> qT/kT/vT in fragment-tiled layout
//              (each 16x32 frag tile = 1KB contiguous, lane-major ->
//               every consumer fragment load is ONE coalesced dwordx4)
//   k_rows   : QK^T + exp + partial row sums, register-direct, no LDS/barrier
//   k_rsum   : rinv[b][i] = 1 / sum_j exp(S[i,j])
//   k_fav    : fused recompute+AV, register-direct, pipelined (above)

typedef _Float16 f16;
typedef _Float16 f16x4v __attribute__((ext_vector_type(4)));
typedef _Float16 f16x8v __attribute__((ext_vector_type(8)));
typedef float f32x4v __attribute__((ext_vector_type(4)));
typedef unsigned int u32;

static __device__ __forceinline__ f32x4v mfma16(f16x8v a, f16x8v b, f32x4v c) {
  // A-frag m=lane&15,k=quad*8+e; B-frag n=lane&15,k=quad*8+e
  // D: col(n)=lane&15, row(m)=quad*4+reg
  return __builtin_amdgcn_mfma_f32_16x16x32_f16(a, b, c, 0, 0, 0);
}

static __device__ __forceinline__ u32 pk2(float a, float b) {
  union { f16 h[2]; u32 u; } cv;
  cv.h[0] = (f16)a; cv.h[1] = (f16)b;   // RNE converts, low half = lower i
  return cv.u;
}

#define AS1q __attribute__((address_space(1)))
#define AS3q __attribute__((address_space(3)))
static __device__ __forceinline__ void gl_lds16(const void* g, void* l) {
  __builtin_amdgcn_global_load_lds((const AS1q unsigned int*)g,
                                   (AS3q unsigned int*)l, 16, 0, 0);
}

// ---------------- kernel 0a: weight convert ----------------
__global__ void k_wcvt(const float* __restrict__ wq, const float* __restrict__ bq,
                       const float* __restrict__ wk, const float* __restrict__ bk,
                       const float* __restrict__ wv, const float* __restrict__ bv,
                       f16* __restrict__ wh, float* __restrict__ bcat) {
  int o = blockIdx.x;          // 512 rows: 0-127 q, 128-255 k, 256-511 v
  int c = threadIdx.x;         // 256
  const float* wrow; float bias;
  if (o < 128)      { wrow = wq + (size_t)o * 256;         bias = bq[o]; }
  else if (o < 256) { wrow = wk + (size_t)(o - 128) * 256; bias = bk[o - 128]; }
  else              { wrow = wv + (size_t)(o - 256) * 256; bias = bv[o - 256]; }
  wh[(size_t)o * 256 + c] = (f16)wrow[c];
  if (c == 0) bcat[o] = bias;
}

// ---------------- kernel 0b: x transpose ----------------
__global__ void k_xsplit(const float* __restrict__ x, f16* __restrict__ xh) {
  __shared__ float t[64][65];
  int b = blockIdx.z, c0 = blockIdx.y * 64, n0 = blockIdx.x * 64;
  int tx = threadIdx.x & 63, ty = threadIdx.x >> 6;
  const float* xb = x + ((size_t)b * 256 + c0) * 4096 + n0;
#pragma unroll
  for (int r = ty; r < 64; r += 4) t[r][tx] = xb[(size_t)r * 4096 + tx];
  __syncthreads();
  f16* dh = xh + ((size_t)b * 4096 + n0) * 256 + c0;
#pragma unroll
  for (int r = ty; r < 64; r += 4)
    dh[(size_t)r * 256 + tx] = (f16)t[tx][r];
}

// ---------------- kernel 1: projections -> fragment-tiled outputs ----------------
//  qT/kT elem addr = b*524288 + t*2048 + kt*512 + qd*128 + (row&15)*8 + e
//    (t = token>>4, d=channel: kt=d>>5, qd=(d>>3)&3, e=d&7)
//  vT   elem addr = b*1048576 + ct*65536 + it2*512 + qd2*128 + (c&15)*8 + e2
//    (ct=c>>4, i: it2=i>>5, qd2=(i>>3)&3, e2=i&7)
__global__ void __launch_bounds__(256, 2)
k_proj(const f16* __restrict__ xh, const f16* __restrict__ wh,
       const float* __restrict__ bcat, f16* __restrict__ qT,
       f16* __restrict__ kT, f16* __restrict__ vT) {
  extern __shared__ char smem[];   // 64KB
  int b = blockIdx.z, m0 = blockIdx.y * 64, n0 = blockIdx.x * 64;
  int tid = threadIdx.x, l = tid & 63, w = tid >> 6;
  int col = l & 15, quad = l >> 4;
  const f16* Ag = xh + ((size_t)b * 4096 + m0) * 256;
  const f16* Wg = wh + (size_t)n0 * 256;
  int rloc = l >> 5;
  int l5 = l & 31;
#pragma unroll
  for (int p = 0; p < 8; p++) {
    int ci = w * 8 + p;
    int r = ci * 2 + rloc;
    int g = l5 ^ (r & 31);
    gl_lds16(Ag + (size_t)r * 256 + g * 8, smem + ci * 1024);
    gl_lds16(Wg + (size_t)r * 256 + g * 8, smem + 32768 + ci * 1024);
  }
  __syncthreads();
  const char* sA = smem;
  const char* sW = smem + 32768;
  f32x4v acc[4] = {};
  int ar = w * 16 + col;
#pragma unroll
  for (int ks = 0; ks < 8; ks++) {
    int G = ks * 4 + quad;
    f16x8v a = *(const f16x8v*)(sA + ar * 512 + ((G ^ (ar & 31)) * 16));
#pragma unroll
    for (int nt = 0; nt < 4; nt++) {
      int wr = nt * 16 + col;
      f16x8v bb = *(const f16x8v*)(sW + wr * 512 + ((G ^ (wr & 31)) * 16));
      acc[nt] = mfma16(a, bb, acc[nt]);
    }
  }
  if (n0 < 256) {
#pragma unroll
    for (int nt = 0; nt < 4; nt++) {
      int o = n0 + nt * 16 + col;
      float bias = bcat[o];
      int d = o & 127;
      f16* dst = (o < 128) ? qT : kT;
      size_t tb = (size_t)b * 524288 + (size_t)(m0 / 16 + w) * 2048 +
                  (size_t)(d >> 5) * 512 + (size_t)((d >> 3) & 3) * 128 + (d & 7);
#pragma unroll
      for (int rg = 0; rg < 4; rg++)
        dst[tb + (quad * 4 + rg) * 8] = (f16)(acc[nt][rg] + bias);
    }
  } else {
    int i2 = w * 16 + quad * 4;              // token offset within m0 block
    int it2 = (m0 + i2) >> 5;
    int qd2 = (i2 >> 3) & 3;
    int e2 = i2 & 7;                          // 0 or 4; rg appends
#pragma unroll
    for (int nt = 0; nt < 4; nt++) {
      int o = n0 + nt * 16 + col;
      float bias = bcat[o];
      int c = o - 256;
      f16x4v pv;
#pragma unroll
      for (int rg = 0; rg < 4; rg++) pv[rg] = (f16)(acc[nt][rg] + bias);
      size_t addr = (size_t)b * 1048576 + (size_t)(c >> 4) * 65536 +
                    (size_t)it2 * 512 + (size_t)qd2 * 128 + (size_t)(c & 15) * 8 + e2;
      *(f16x4v*)&vT[addr] = pv;
    }
  }
}

// ---------------- kernel 2: row sums of exp(S), register-direct tiled ----------------
// wg = (jblk, ih, b), 512 thr. Wave (ti=w&3, half=w>>2): K j-tile pair
// resident in regs; 32 i-iters, Q frags dbuf-prefetched; exp + in-wave
// j-reduction. partial[b][jblk*2+half][i] = sum of 32 exp. No LDS/barriers.
__global__ void __launch_bounds__(512, 2)
k_rows(const f16* __restrict__ qT, const f16* __restrict__ kT,
       float* __restrict__ partial) {
  int jblk = blockIdx.x, ih = blockIdx.y, b = blockIdx.z;
  int tid = threadIdx.x, l = tid & 63, w = tid >> 6;
  int col = l & 15;
  int ti = w & 3, half = w >> 2, tjb = half * 2;
  const f16* ktb = kT + (size_t)b * 524288 + (size_t)(jblk * 4 + tjb) * 2048 + l * 8;
  const f16* qtb = qT + (size_t)b * 524288 + (size_t)ti * 2048 + l * 8;
  f16x8v ka0[4], ka1[4];
#pragma unroll
  for (int ks = 0; ks < 4; ks++) {
    ka0[ks] = *(const f16x8v*)(ktb + ks * 512);
    ka1[ks] = *(const f16x8v*)(ktb + 2048 + ks * 512);
  }
  float* pout = partial + ((size_t)(b * 64 + jblk) * 2 + half) * 4096 + ti * 16 + col;
  int it0 = ih * 32;
  f16x8v qfA[4], qfB[4];
#pragma unroll
  for (int ks = 0; ks < 4; ks++)
    qfA[ks] = *(const f16x8v*)(qtb + (size_t)it0 * 8192 + ks * 512);

#define ROWS_BODY(IT, QF, QN, PREF)                                           \
  {                                                                           \
    if (PREF) {                                                               \
      _Pragma("unroll") for (int ks = 0; ks < 4; ks++)                        \
        QN[ks] = *(const f16x8v*)(qtb + (size_t)((IT) + 1) * 8192 + ks * 512);\
    }                                                                         \
    f32x4v s0 = {}, s1 = {};                                                  \
    _Pragma("unroll") for (int ks = 0; ks < 4; ks++) {                        \
      s0 = mfma16(ka0[ks], QF[ks], s0);                                       \
      s1 = mfma16(ka1[ks], QF[ks], s1);                                       \
    }                                                                         \
    float t = 0.f;                                                            \
    _Pragma("unroll") for (int rg = 0; rg < 4; rg++)                          \
      t += __expf(s0[rg]) + __expf(s1[rg]);                                   \
    t += __shfl_xor(t, 16);                                                   \
    t += __shfl_xor(t, 32);                                                   \
    if (l < 16) pout[(size_t)(IT) * 64] = t;                                  \
  }

  for (int itp = 0; itp < 16; itp++) {
    int itA = it0 + itp * 2;
    ROWS_BODY(itA, qfA, qfB, true)
    ROWS_BODY(itA + 1, qfB, qfA, itp < 15)
  }
#undef ROWS_BODY
}

// ---------------- kernel 3: combine partials -> rinv = 1/rowsum ----------------
__global__ void k_rsum(const float* __restrict__ partial, float* __restrict__ rinv) {
  int b = blockIdx.y;
  int i = blockIdx.x * 256 + threadIdx.x;
  const float* p = partial + (size_t)b * 128 * 4096 + i;
  float s = 0.f;
#pragma unroll 8
  for (int jb = 0; jb < 128; jb++) s += p[(size_t)jb * 4096];
  rinv[(size_t)b * 4096 + i] = 1.0f / s;
}

// ---------------- kernel 4: fused recompute + AV, pipelined ----------------
// Per wg: batch b, j-cols [j0,j0+64), all 256 c. Steady-state iter t:
//   exp(S(t))*rinv -> 4 packed b32 sE[t&1] writes   (regs from last iter)
//   prefetch qf(t+2), vf(t+1), rv(t+1)              (VMEM, clamped)
//   S(t+1) = mfma(Q(t+1), K)                        (overlaps the exp above)
//   lgkmcnt(0); s_barrier                           (one barrier/iter)
//   acc += mfma(V(t), E'(t)^T)                      (ds_read sE + MFMA)
// QK uses A=Q,B=K: lane holds S[i=quad*4+rg][j=col] -> rg pairs pack to b32.
__global__ void __launch_bounds__(512, 2)
k_fav(const f16* __restrict__ qT, const f16* __restrict__ kT,
      const f16* __restrict__ vT, const float* __restrict__ rinv,
      const float* __restrict__ x, const float* __restrict__ gamma,
      float* __restrict__ out) {
  __shared__ f16 sE[2][4096];   // [buf][64 j][64 i], 8-elem i-groups XOR(j&7)
  // XCD-chunked swizzle: 256 wgs, 8 XCDs -> contiguous 32-wg slice per XCD.
  int wg = blockIdx.x;
  int lg = (wg & 7) * 32 + (wg >> 3);
  int b = lg >> 6, j0 = (lg & 63) * 64;
  int tid = threadIdx.x, l = tid & 63, w = tid >> 6;
  int col = l & 15, quad = l >> 4;
  int ti = w & 3, tjb = (w >> 2) * 2;
  const f16* ktb = kT + (size_t)b * 524288 + (size_t)(j0 / 16 + tjb) * 2048 + l * 8;
  const f16* qtb = qT + (size_t)b * 524288 + (size_t)ti * 2048 + l * 8;
  const f16* vtb = vT + (size_t)b * 1048576 + (size_t)(w * 2) * 65536 + l * 8;
  const float* rp = rinv + (size_t)b * 4096 + ti * 16 + quad * 4;
  // K fragments: resident whole kernel
  f16x8v ka0[4], ka1[4];
#pragma unroll
  for (int ks = 0; ks < 4; ks++) {
    ka0[ks] = *(const f16x8v*)(ktb + ks * 512);
    ka1[ks] = *(const f16x8v*)(ktb + 2048 + ks * 512);
  }
  f16x8v qfA[4], qfB[4], vfA[2][2], vfB[2][2];
  f32x4v scA[2], scB[2], rvA, rvB;
  // prologue: S(0) from qf(0); then qf(1), vf(0), rv(0)
#pragma unroll
  for (int ks = 0; ks < 4; ks++) qfA[ks] = *(const f16x8v*)(qtb + ks * 512);
  scA[0] = (f32x4v){}; scA[1] = (f32x4v){};
#pragma unroll
  for (int ks = 0; ks < 4; ks++) {
    scA[0] = mfma16(qfA[ks], ka0[ks], scA[0]);
    scA[1] = mfma16(qfA[ks], ka1[ks], scA[1]);
  }
#pragma unroll
  for (int ks = 0; ks < 4; ks++)
    qfB[ks] = *(const f16x8v*)(qtb + 8192 + ks * 512);
#pragma unroll
  for (int mt = 0; mt < 2; mt++)
#pragma unroll
    for (int ks = 0; ks < 2; ks++)
      vfA[mt][ks] = *(const f16x8v*)(vtb + mt * 65536 + ks * 512);
  rvA = *(const f32x4v*)rp;
  f32x4v acc[2][4] = {};
  int jr0 = tjb * 16 + col;   // sE row of this lane's j-tile 0
  // write swizzle: i = ti*16 + quad*4 + {0..3}; ig=i>>3, i&7 reproduce read XOR
  int swz = (((ti * 2 + (quad >> 1)) ^ (col & 7)) * 8) + (quad & 1) * 4;

#define FAV_IT(IT, SC, SN, QKF, QPF, VF, VN, RV, RN, SEB)                      \
  {                                                                            \
    /* exp + packed sE writes for tile IT (independent of QK below) */         \
    u32 w00 = pk2(__expf(SC[0][0]) * RV[0], __expf(SC[0][1]) * RV[1]);         \
    u32 w01 = pk2(__expf(SC[0][2]) * RV[2], __expf(SC[0][3]) * RV[3]);         \
    u32 w10 = pk2(__expf(SC[1][0]) * RV[0], __expf(SC[1][1]) * RV[1]);         \
    u32 w11 = pk2(__expf(SC[1][2]) * RV[2], __expf(SC[1][3]) * RV[3]);         \
    *(u32*)&sE[SEB][jr0 * 64 + swz] = w00;                                     \
    *(u32*)&sE[SEB][jr0 * 64 + swz + 2] = w01;                                 \
    *(u32*)&sE[SEB][(jr0 + 16) * 64 + swz] = w10;                              \
    *(u32*)&sE[SEB][(jr0 + 16) * 64 + swz + 2] = w11;                          \
    /* prefetch qf(IT+2), vf(IT+1), rv(IT+1) — clamped, no branches */         \
    {                                                                          \
      int qit = (IT) + 2 > 63 ? 63 : (IT) + 2;                                 \
      int vit = (IT) + 1 > 63 ? 63 : (IT) + 1;                                 \
      _Pragma("unroll") for (int ks = 0; ks < 4; ks++)                         \
        QPF[ks] = *(const f16x8v*)(qtb + (size_t)qit * 8192 + ks * 512);       \
      _Pragma("unroll") for (int mt = 0; mt < 2; mt++)                         \
        _Pragma("unroll") for (int ks = 0; ks < 2; ks++)                       \
          VN[mt][ks] = *(const f16x8v*)(vtb + mt * 65536 +                     \
                                        (size_t)(vit * 2 + ks) * 512);         \
      RN = *(const f32x4v*)(rp + (size_t)vit * 64);                            \
    }                                                                          \
    /* QK for tile IT+1 (junk at IT=63, never consumed) */                     \
    SN[0] = (f32x4v){}; SN[1] = (f32x4v){};                                    \
    _Pragma("unroll") for (int ks = 0; ks < 4; ks++) {                         \
      SN[0] = mfma16(QKF[ks], ka0[ks], SN[0]);                                 \
      SN[1] = mfma16(QKF[ks], ka1[ks], SN[1]);                                 \
    }                                                                          \
    asm volatile("s_waitcnt lgkmcnt(0)\n\ts_barrier" ::: "memory");            \
    /* AV for tile IT */                                                       \
    _Pragma("unroll") for (int ks = 0; ks < 2; ks++) {                         \
      int sw = ((ks * 4 + quad) ^ (col & 7)) * 8;                              \
      f16x8v e0 = *(const f16x8v*)&sE[SEB][col * 64 + sw];                     \
      f16x8v e1 = *(const f16x8v*)&sE[SEB][(16 + col) * 64 + sw];              \
      f16x8v e2 = *(const f16x8v*)&sE[SEB][(32 + col) * 64 + sw];              \
      f16x8v e3 = *(const f16x8v*)&sE[SEB][(48 + col) * 64 + sw];              \
      acc[0][0] = mfma16(VF[0][ks], e0, acc[0][0]);                            \
      acc[0][1] = mfma16(VF[0][ks], e1, acc[0][1]);                            \
      acc[0][2] = mfma16(VF[0][ks], e2, acc[0][2]);                            \
      acc[0][3] = mfma16(VF[0][ks], e3, acc[0][3]);                            \
      acc[1][0] = mfma16(VF[1][ks], e0, acc[1][0]);                            \
      acc[1][1] = mfma16(VF[1][ks], e1, acc[1][1]);                            \
      acc[1][2] = mfma16(VF[1][ks], e2, acc[1][2]);                            \
      acc[1][3] = mfma16(VF[1][ks], e3, acc[1][3]);                            \
    }                                                                          \
  }

  for (int itp = 0; itp < 32; itp++) {
    int itA = itp * 2;
    FAV_IT(itA,     scA, scB, qfB, qfA, vfA, vfB, rvA, rvB, 0)
    FAV_IT(itA + 1, scB, scA, qfA, qfB, vfB, vfA, rvB, rvA, 1)
  }
#undef FAV_IT

  float gm = gamma[0];
  const float* xb = x + (size_t)b * 256 * 4096;
  float* ob = out + (size_t)b * 256 * 4096;
#pragma unroll
  for (int mt = 0; mt < 2; mt++)
#pragma unroll
    for (int jt = 0; jt < 4; jt++) {
      int c = w * 32 + mt * 16 + quad * 4;
      int j = j0 + jt * 16 + col;
#pragma unroll
      for (int rg = 0; rg < 4; rg++) {
        size_t off = (size_t)(c + rg) * 4096 + j;
        ob[off] = gm * acc[mt][jt][rg] + xb[off];
      }
    }
}

extern "C" void kernel_launch(void* const* d_in, const int* in_sizes, int n_in,
                              void* d_out, int out_size, void* d_ws, size_t ws_size,
                              hipStream_t stream) {
  (void)in_sizes; (void)n_in; (void)out_size; (void)ws_size;
  const float* x  = (const float*)d_in[0];
  const float* wq = (const float*)d_in[1];
  const float* bq = (const float*)d_in[2];
  const float* wk = (const float*)d_in[3];
  const float* bk = (const float*)d_in[4];
  const float* wv = (const float*)d_in[5];
  const float* bv = (const float*)d_in[6];
  const float* gm = (const float*)d_in[7];
  float* out = (float*)d_out;

  char* ws = (char*)d_ws;
  f16*  xh = (f16*)ws;                          // 8 MB
  f16*  qT = (f16*)(ws + 8388608);              // 4 MB fragment-tiled Q
  f16*  kT = (f16*)(ws + 12582912);             // 4 MB fragment-tiled K
  f16*  vT = (f16*)(ws + 16777216);             // 8 MB fragment-tiled V
  f16*  wh = (f16*)(ws + 25165824);             // 256 KB
  float* bcat    = (float*)(ws + 25427968);     // 2 KB
  float* rinv    = (float*)(ws + 25430016);     // 64 KB
  float* partial = (float*)(ws + 25495552);     // 8 MB: [b][128][4096]

  hipLaunchKernelGGL(k_wcvt, dim3(512), dim3(256), 0, stream, wq, bq, wk, bk, wv, bv, wh, bcat);
  hipLaunchKernelGGL(k_xsplit, dim3(64, 4, 4), dim3(256), 0, stream, x, xh);
  hipLaunchKernelGGL(k_proj, dim3(8, 64, 4), dim3(256), 65536, stream, xh, wh, bcat, qT, kT, vT);
  hipLaunchKernelGGL(k_rows, dim3(64, 2, 4), dim3(512), 0, stream, qT, kT, partial);
  hipLaunchKernelGGL(k_rsum, dim3(16, 4), dim3(256), 0, stream, partial, rinv);
  hipLaunchKernelGGL(k_fav, dim3(256), dim3(512), 0, stream, qT, kT, vT, rinv, x, gm, out);
}

// Round 7
// 184.341 us; speedup vs baseline: 1.0684x; 1.0684x over previous
//
#include <hip/hip_runtime.h>
#include <hip/hip_bf16.h>

// ConvSelfAttentionModule: B=4, C=256, CQK=128, N=4096 (64x64), fp32 in/out.
// R15 = R12/R4 (proven 191us, passed) + widened k_rows ONLY.
// R6 lesson: j-split k_fav raced on graph replay (passed once, diverged
// post-timing) -> k_fav reverted to the twice-proven R4 body, byte-identical.
// k_rows was ~60us (as big as k_fav): each wg re-read a 2MB Q-half for only
// 64 j -> 1 GB L2 traffic. Now each wave holds 4 K j-tiles resident
// (ka[4][4], 64 VGPR) -> 128 j per wg, Q traffic halved, MFMA per Q-load
// doubled. Grid (32,2,4)=256 wgs; partial shrinks to [b][64][4096].
//   k_wcvt   : W -> f16
//   k_xsplit : transpose x[b][c][n] -> xT[b][n][c] f16
//   k_proj   : f16 MFMA GEMM -> qT/kT/vT in fragment-tiled layout
//              (each 16x32 frag tile = 1KB contiguous, lane-major ->
//               every consumer fragment load is ONE coalesced dwordx4)
//   k_rows   : QK^T + exp + partial row sums, register-direct, no LDS/barrier
//   k_rsum   : rinv[b][i] = 1 / sum_j exp(S[i,j])  (64 partials)
//   k_fav    : fused recompute+AV, register-direct, sE 16KB dbuf,
//              one lgkm-only barrier/iter (R2/R4-verified safe)

typedef _Float16 f16;
typedef _Float16 f16x4v __attribute__((ext_vector_type(4)));
typedef _Float16 f16x8v __attribute__((ext_vector_type(8)));
typedef float f32x4v __attribute__((ext_vector_type(4)));

static __device__ __forceinline__ f32x4v mfma16(f16x8v a, f16x8v b, f32x4v c) {
  // A-frag m=lane&15,k=quad*8+e; B-frag n=lane&15,k=quad*8+e
  // D: col(n)=lane&15, row(m)=quad*4+reg
  return __builtin_amdgcn_mfma_f32_16x16x32_f16(a, b, c, 0, 0, 0);
}

#define AS1q __attribute__((address_space(1)))
#define AS3q __attribute__((address_space(3)))
static __device__ __forceinline__ void gl_lds16(const void* g, void* l) {
  __builtin_amdgcn_global_load_lds((const AS1q unsigned int*)g,
                                   (AS3q unsigned int*)l, 16, 0, 0);
}

// ---------------- kernel 0a: weight convert ----------------
__global__ void k_wcvt(const float* __restrict__ wq, const float* __restrict__ bq,
                       const float* __restrict__ wk, const float* __restrict__ bk,
                       const float* __restrict__ wv, const float* __restrict__ bv,
                       f16* __restrict__ wh, float* __restrict__ bcat) {
  int o = blockIdx.x;          // 512 rows: 0-127 q, 128-255 k, 256-511 v
  int c = threadIdx.x;         // 256
  const float* wrow; float bias;
  if (o < 128)      { wrow = wq + (size_t)o * 256;         bias = bq[o]; }
  else if (o < 256) { wrow = wk + (size_t)(o - 128) * 256; bias = bk[o - 128]; }
  else              { wrow = wv + (size_t)(o - 256) * 256; bias = bv[o - 256]; }
  wh[(size_t)o * 256 + c] = (f16)wrow[c];
  if (c == 0) bcat[o] = bias;
}

// ---------------- kernel 0b: x transpose ----------------
__global__ void k_xsplit(const float* __restrict__ x, f16* __restrict__ xh) {
  __shared__ float t[64][65];
  int b = blockIdx.z, c0 = blockIdx.y * 64, n0 = blockIdx.x * 64;
  int tx = threadIdx.x & 63, ty = threadIdx.x >> 6;
  const float* xb = x + ((size_t)b * 256 + c0) * 4096 + n0;
#pragma unroll
  for (int r = ty; r < 64; r += 4) t[r][tx] = xb[(size_t)r * 4096 + tx];
  __syncthreads();
  f16* dh = xh + ((size_t)b * 4096 + n0) * 256 + c0;
#pragma unroll
  for (int r = ty; r < 64; r += 4)
    dh[(size_t)r * 256 + tx] = (f16)t[tx][r];
}

// ---------------- kernel 1: projections -> fragment-tiled outputs ----------------
//  qT/kT elem addr = b*524288 + t*2048 + kt*512 + qd*128 + (row&15)*8 + e
//    (t = token>>4, d=channel: kt=d>>5, qd=(d>>3)&3, e=d&7)
//  vT   elem addr = b*1048576 + ct*65536 + it2*512 + qd2*128 + (c&15)*8 + e2
//    (ct=c>>4, i: it2=i>>5, qd2=(i>>3)&3, e2=i&7)
__global__ void __launch_bounds__(256, 2)
k_proj(const f16* __restrict__ xh, const f16* __restrict__ wh,
       const float* __restrict__ bcat, f16* __restrict__ qT,
       f16* __restrict__ kT, f16* __restrict__ vT) {
  extern __shared__ char smem[];   // 64KB
  int b = blockIdx.z, m0 = blockIdx.y * 64, n0 = blockIdx.x * 64;
  int tid = threadIdx.x, l = tid & 63, w = tid >> 6;
  int col = l & 15, quad = l >> 4;
  const f16* Ag = xh + ((size_t)b * 4096 + m0) * 256;
  const f16* Wg = wh + (size_t)n0 * 256;
  int rloc = l >> 5;
  int l5 = l & 31;
#pragma unroll
  for (int p = 0; p < 8; p++) {
    int ci = w * 8 + p;
    int r = ci * 2 + rloc;
    int g = l5 ^ (r & 31);
    gl_lds16(Ag + (size_t)r * 256 + g * 8, smem + ci * 1024);
    gl_lds16(Wg + (size_t)r * 256 + g * 8, smem + 32768 + ci * 1024);
  }
  __syncthreads();
  const char* sA = smem;
  const char* sW = smem + 32768;
  f32x4v acc[4] = {};
  int ar = w * 16 + col;
#pragma unroll
  for (int ks = 0; ks < 8; ks++) {
    int G = ks * 4 + quad;
    f16x8v a = *(const f16x8v*)(sA + ar * 512 + ((G ^ (ar & 31)) * 16));
#pragma unroll
    for (int nt = 0; nt < 4; nt++) {
      int wr = nt * 16 + col;
      f16x8v bb = *(const f16x8v*)(sW + wr * 512 + ((G ^ (wr & 31)) * 16));
      acc[nt] = mfma16(a, bb, acc[nt]);
    }
  }
  if (n0 < 256) {
#pragma unroll
    for (int nt = 0; nt < 4; nt++) {
      int o = n0 + nt * 16 + col;
      float bias = bcat[o];
      int d = o & 127;
      f16* dst = (o < 128) ? qT : kT;
      size_t tb = (size_t)b * 524288 + (size_t)(m0 / 16 + w) * 2048 +
                  (size_t)(d >> 5) * 512 + (size_t)((d >> 3) & 3) * 128 + (d & 7);
#pragma unroll
      for (int rg = 0; rg < 4; rg++)
        dst[tb + (quad * 4 + rg) * 8] = (f16)(acc[nt][rg] + bias);
    }
  } else {
    int i2 = w * 16 + quad * 4;              // token offset within m0 block
    int it2 = (m0 + i2) >> 5;
    int qd2 = (i2 >> 3) & 3;
    int e2 = i2 & 7;                          // 0 or 4; rg appends
#pragma unroll
    for (int nt = 0; nt < 4; nt++) {
      int o = n0 + nt * 16 + col;
      float bias = bcat[o];
      int c = o - 256;
      f16x4v pv;
#pragma unroll
      for (int rg = 0; rg < 4; rg++) pv[rg] = (f16)(acc[nt][rg] + bias);
      size_t addr = (size_t)b * 1048576 + (size_t)(c >> 4) * 65536 +
                    (size_t)it2 * 512 + (size_t)qd2 * 128 + (size_t)(c & 15) * 8 + e2;
      *(f16x4v*)&vT[addr] = pv;
    }
  }
}

// ---------------- kernel 2: row sums of exp(S), widened (128 j per wg) ----------------
// wg = (jblk [0,32), ih [0,2), b), 512 thr. Wave (ti=w&3, jh=w>>2): holds
// FOUR K j-tiles resident (j-tiles jblk*8+jh*4 .. +3 = 64 j), loops 32
// i-iters (i-tile = IT*4+ti), Q frags dbuf-prefetched; 16 MFMA per 4 Q-loads
// (2x the old amortization, half the Q L2 traffic). exp + in-register jt/rg
// sum + shfl over quad. partial[b][jblk*2+jh][i] = sum over 64 j of exp.
// No LDS, no barriers. ~130 VGPR, safe under (512,2) cap 256.
__global__ void __launch_bounds__(512, 2)
k_rows(const f16* __restrict__ qT, const f16* __restrict__ kT,
       float* __restrict__ partial) {
  int jblk = blockIdx.x, ih = blockIdx.y, b = blockIdx.z;
  int tid = threadIdx.x, l = tid & 63, w = tid >> 6;
  int col = l & 15;
  int ti = w & 3, jh = w >> 2;
  const f16* ktb = kT + (size_t)b * 524288 + (size_t)(jblk * 8 + jh * 4) * 2048 + l * 8;
  const f16* qtb = qT + (size_t)b * 524288 + (size_t)ti * 2048 + l * 8;
  f16x8v ka[4][4];
#pragma unroll
  for (int jt = 0; jt < 4; jt++)
#pragma unroll
    for (int ks = 0; ks < 4; ks++)
      ka[jt][ks] = *(const f16x8v*)(ktb + jt * 2048 + ks * 512);
  float* pout = partial + ((size_t)(b * 32 + jblk) * 2 + jh) * 4096 + ti * 16 + col;
  int it0 = ih * 32;
  f16x8v qfA[4], qfB[4];
#pragma unroll
  for (int ks = 0; ks < 4; ks++)
    qfA[ks] = *(const f16x8v*)(qtb + (size_t)it0 * 8192 + ks * 512);

#define ROWS_BODY(IT, QF, QN, PREF)                                           \
  {                                                                           \
    if (PREF) {                                                               \
      _Pragma("unroll") for (int ks = 0; ks < 4; ks++)                        \
        QN[ks] = *(const f16x8v*)(qtb + (size_t)((IT) + 1) * 8192 + ks * 512);\
    }                                                                         \
    f32x4v s[4] = {};                                                         \
    _Pragma("unroll") for (int ks = 0; ks < 4; ks++) {                        \
      s[0] = mfma16(ka[0][ks], QF[ks], s[0]);                                 \
      s[1] = mfma16(ka[1][ks], QF[ks], s[1]);                                 \
      s[2] = mfma16(ka[2][ks], QF[ks], s[2]);                                 \
      s[3] = mfma16(ka[3][ks], QF[ks], s[3]);                                 \
    }                                                                         \
    float t = 0.f;                                                            \
    _Pragma("unroll") for (int jt = 0; jt < 4; jt++)                          \
      _Pragma("unroll") for (int rg = 0; rg < 4; rg++)                        \
        t += __expf(s[jt][rg]);                                               \
    t += __shfl_xor(t, 16);                                                   \
    t += __shfl_xor(t, 32);                                                   \
    if (l < 16) pout[(size_t)(IT) * 64] = t;                                  \
  }

  for (int itp = 0; itp < 16; itp++) {
    int itA = it0 + itp * 2;
    ROWS_BODY(itA, qfA, qfB, true)
    ROWS_BODY(itA + 1, qfB, qfA, itp < 15)
  }
#undef ROWS_BODY
}

// ---------------- kernel 3: combine partials -> rinv = 1/rowsum ----------------
__global__ void k_rsum(const float* __restrict__ partial, float* __restrict__ rinv) {
  int b = blockIdx.y;
  int i = blockIdx.x * 256 + threadIdx.x;
  const float* p = partial + (size_t)b * 64 * 4096 + i;
  float s = 0.f;
#pragma unroll 8
  for (int jb = 0; jb < 64; jb++) s += p[(size_t)jb * 4096];
  rinv[(size_t)b * 4096 + i] = 1.0f / s;
}

// ---------------- kernel 4: fused recompute + AV, register-direct tiled ----------------
// Per wg: batch b, j-cols [j0,j0+64), all 256 c. Loop i in 64-steps:
//   S^T = mfma(K_regs, Q_regs);  E' = exp(S)*rinv -> sE (dbuf, swizzled)
//   acc[c][j] += mfma(V_regs, E'^T)
// All frag loads = coalesced 1KB from tiled layouts, prefetched 1 tile ahead.
// One lgkm-only s_barrier per iter (sE dbuf makes WAR safe — R2/R4-verified).
// BYTE-IDENTICAL to the R4 kernel that measured 62.2us and passed.
__global__ void __launch_bounds__(512, 2)
k_fav(const f16* __restrict__ qT, const f16* __restrict__ kT,
      const f16* __restrict__ vT, const float* __restrict__ rinv,
      const float* __restrict__ x, const float* __restrict__ gamma,
      float* __restrict__ out) {
  __shared__ f16 sE[2][4096];   // [buf][64 j][64 i], 8-elem i-groups XOR(j&7)
  // XCD-chunked swizzle: 256 wgs, 8 XCDs -> contiguous 32-wg slice per XCD.
  int wg = blockIdx.x;
  int lg = (wg & 7) * 32 + (wg >> 3);
  int b = lg >> 6, j0 = (lg & 63) * 64;
  int tid = threadIdx.x, l = tid & 63, w = tid >> 6;
  int col = l & 15, quad = l >> 4;
  int ti = w & 3, tjb = (w >> 2) * 2;
  const f16* ktb = kT + (size_t)b * 524288 + (size_t)(j0 / 16 + tjb) * 2048 + l * 8;
  const f16* qtb = qT + (size_t)b * 524288 + (size_t)ti * 2048 + l * 8;
  const f16* vtb = vT + (size_t)b * 1048576 + (size_t)(w * 2) * 65536 + l * 8;
  const float* rp = rinv + (size_t)b * 4096 + ti * 16 + col;
  // K fragments: resident whole kernel
  f16x8v ka0[4], ka1[4];
#pragma unroll
  for (int ks = 0; ks < 4; ks++) {
    ka0[ks] = *(const f16x8v*)(ktb + ks * 512);
    ka1[ks] = *(const f16x8v*)(ktb + 2048 + ks * 512);
  }
  f16x8v qfA[4], qfB[4], vfA[2][2], vfB[2][2];
  float rvA, rvB;
#pragma unroll
  for (int ks = 0; ks < 4; ks++) qfA[ks] = *(const f16x8v*)(qtb + ks * 512);
#pragma unroll
  for (int mt = 0; mt < 2; mt++)
#pragma unroll
    for (int ks = 0; ks < 2; ks++)
      vfA[mt][ks] = *(const f16x8v*)(vtb + mt * 65536 + ks * 512);
  rvA = rp[0];
  f32x4v acc[2][4] = {};
  int ig = ti * 2 + (col >> 3);
  int i_lo = col & 7;

#define FAV_BODY(IT, QF, VF, RV, QN, VN, RN, PREF, SEB)                        \
  {                                                                            \
    if (PREF) {                                                                \
      _Pragma("unroll") for (int ks = 0; ks < 4; ks++)                         \
        QN[ks] = *(const f16x8v*)(qtb + (size_t)((IT) + 1) * 8192 + ks * 512); \
      _Pragma("unroll") for (int mt = 0; mt < 2; mt++)                         \
        _Pragma("unroll") for (int ks = 0; ks < 2; ks++)                       \
          VN[mt][ks] = *(const f16x8v*)(vtb + mt * 65536 +                     \
                                        (size_t)(((IT) + 1) * 2 + ks) * 512);  \
      RN = rp[((IT) + 1) * 64];                                                \
    }                                                                          \
    f32x4v s0 = {}, s1 = {};                                                   \
    _Pragma("unroll") for (int ks = 0; ks < 4; ks++) {                         \
      s0 = mfma16(ka0[ks], QF[ks], s0);                                        \
      s1 = mfma16(ka1[ks], QF[ks], s1);                                        \
    }                                                                          \
    _Pragma("unroll") for (int rg = 0; rg < 4; rg++) {                         \
      int jl0 = tjb * 16 + quad * 4 + rg;                                      \
      sE[SEB][jl0 * 64 + ((ig ^ (jl0 & 7)) * 8) + i_lo] = (f16)(__expf(s0[rg]) * RV); \
      sE[SEB][(jl0 + 16) * 64 + ((ig ^ (jl0 & 7)) * 8) + i_lo] = (f16)(__expf(s1[rg]) * RV); \
    }                                                                          \
    asm volatile("s_waitcnt lgkmcnt(0)\n\ts_barrier" ::: "memory");            \
    _Pragma("unroll") for (int ks = 0; ks < 2; ks++) {                         \
      int sw = ((ks * 4 + quad) ^ (col & 7)) * 8;                              \
      f16x8v e0 = *(const f16x8v*)&sE[SEB][col * 64 + sw];                     \
      f16x8v e1 = *(const f16x8v*)&sE[SEB][(16 + col) * 64 + sw];              \
      f16x8v e2 = *(const f16x8v*)&sE[SEB][(32 + col) * 64 + sw];              \
      f16x8v e3 = *(const f16x8v*)&sE[SEB][(48 + col) * 64 + sw];              \
      acc[0][0] = mfma16(VF[0][ks], e0, acc[0][0]);                            \
      acc[0][1] = mfma16(VF[0][ks], e1, acc[0][1]);                            \
      acc[0][2] = mfma16(VF[0][ks], e2, acc[0][2]);                            \
      acc[0][3] = mfma16(VF[0][ks], e3, acc[0][3]);                            \
      acc[1][0] = mfma16(VF[1][ks], e0, acc[1][0]);                            \
      acc[1][1] = mfma16(VF[1][ks], e1, acc[1][1]);                            \
      acc[1][2] = mfma16(VF[1][ks], e2, acc[1][2]);                            \
      acc[1][3] = mfma16(VF[1][ks], e3, acc[1][3]);                            \
    }                                                                          \
  }

  for (int itp = 0; itp < 32; itp++) {
    int itA = itp * 2;
    FAV_BODY(itA, qfA, vfA, rvA, qfB, vfB, rvB, true, 0)
    FAV_BODY(itA + 1, qfB, vfB, rvB, qfA, vfA, rvA, itp < 31, 1)
  }
#undef FAV_BODY

  float gm = gamma[0];
  const float* xb = x + (size_t)b * 256 * 4096;
  float* ob = out + (size_t)b * 256 * 4096;
#pragma unroll
  for (int mt = 0; mt < 2; mt++)
#pragma unroll
    for (int jt = 0; jt < 4; jt++) {
      int c = w * 32 + mt * 16 + quad * 4;
      int j = j0 + jt * 16 + col;
#pragma unroll
      for (int rg = 0; rg < 4; rg++) {
        size_t off = (size_t)(c + rg) * 4096 + j;
        ob[off] = gm * acc[mt][jt][rg] + xb[off];
      }
    }
}

extern "C" void kernel_launch(void* const* d_in, const int* in_sizes, int n_in,
                              void* d_out, int out_size, void* d_ws, size_t ws_size,
                              hipStream_t stream) {
  (void)in_sizes; (void)n_in; (void)out_size; (void)ws_size;
  const float* x  = (const float*)d_in[0];
  const float* wq = (const float*)d_in[1];
  const float* bq = (const float*)d_in[2];
  const float* wk = (const float*)d_in[3];
  const float* bk = (const float*)d_in[4];
  const float* wv = (const float*)d_in[5];
  const float* bv = (const float*)d_in[6];
  const float* gm = (const float*)d_in[7];
  float* out = (float*)d_out;

  char* ws = (char*)d_ws;
  f16*  xh = (f16*)ws;                          // 8 MB
  f16*  qT = (f16*)(ws + 8388608);              // 4 MB fragment-tiled Q
  f16*  kT = (f16*)(ws + 12582912);             // 4 MB fragment-tiled K
  f16*  vT = (f16*)(ws + 16777216);             // 8 MB fragment-tiled V
  f16*  wh = (f16*)(ws + 25165824);             // 256 KB
  float* bcat    = (float*)(ws + 25427968);     // 2 KB
  float* rinv    = (float*)(ws + 25430016);     // 64 KB
  float* partial = (float*)(ws + 25495552);     // 4 MB: [b][64][4096]

  hipLaunchKernelGGL(k_wcvt, dim3(512), dim3(256), 0, stream, wq, bq, wk, bk, wv, bv, wh, bcat);
  hipLaunchKernelGGL(k_xsplit, dim3(64, 4, 4), dim3(256), 0, stream, x, xh);
  hipLaunchKernelGGL(k_proj, dim3(8, 64, 4), dim3(256), 65536, stream, xh, wh, bcat, qT, kT, vT);
  hipLaunchKernelGGL(k_rows, dim3(32, 2, 4), dim3(512), 0, stream, qT, kT, partial);
  hipLaunchKernelGGL(k_rsum, dim3(16, 4), dim3(256), 0, stream, partial, rinv);
  hipLaunchKernelGGL(k_fav, dim3(256), dim3(512), 0, stream, qT, kT, vT, rinv, x, gm, out);
}

// Round 8
// 178.439 us; speedup vs baseline: 1.1038x; 1.0331x over previous
//
#include <hip/hip_runtime.h>
#include <hip/hip_bf16.h>

// ConvSelfAttentionModule: B=4, C=256, CQK=128, N=4096 (64x64), fp32 in/out.
// R16 = R15 (proven 184.3us) + register-direct k_proj.
// k_proj staged 128MB through LDS (64KB x 2048 wgs, 2 barriers) for 4.3 GF of
// MFMA. Fix = same cure as R11: fragment-tiled producer layouts. k_wcvt writes
// W fragment-tiled, k_xsplit writes xh fragment-tiled; k_proj becomes the
// k_rows pattern (W-frags resident, A-frags dbuf reg-prefetched, no LDS, no
// barriers). Consumers k_rows/k_fav and qT/kT/vT layouts BYTE-IDENTICAL to
// the passing R15 kernel.
//   frag-tile addressing (16 rows x 32 k per 1KB tile, lane-major):
//     tile elem addr = tile*T + ks*512 + quad*128 + col*8 + e
//     (row = tile*16+col, k = ks*32+quad*8+e) -> frag load = base + l*8
//   k_wcvt   : W -> f16 fragment-tiled wT[o-tile 32][4096]
//   k_xsplit : x -> xTf[b][t-tile 256][4096] f16 fragment-tiled
//   k_rows   : QK^T + exp + partial row sums (widened, 128 j/wg) [R15]
//   k_rsum   : rinv[b][i] = 1 / sum_j exp(S[i,j])  (64 partials) [R15]
//   k_fav    : fused recompute+AV, sE 16KB dbuf, 1 lgkm barrier/iter [R4]

typedef _Float16 f16;
typedef _Float16 f16x4v __attribute__((ext_vector_type(4)));
typedef _Float16 f16x8v __attribute__((ext_vector_type(8)));
typedef float f32x4v __attribute__((ext_vector_type(4)));

static __device__ __forceinline__ f32x4v mfma16(f16x8v a, f16x8v b, f32x4v c) {
  // A-frag m=lane&15,k=quad*8+e; B-frag n=lane&15,k=quad*8+e
  // D: col(n)=lane&15, row(m)=quad*4+reg
  return __builtin_amdgcn_mfma_f32_16x16x32_f16(a, b, c, 0, 0, 0);
}

// ---------------- kernel 0a: weight convert -> fragment-tiled ----------------
// wT elem (o,c): (o>>4)*4096 + (c>>5)*512 + ((c>>3)&3)*128 + (o&15)*8 + (c&7)
__global__ void k_wcvt(const float* __restrict__ wq, const float* __restrict__ bq,
                       const float* __restrict__ wk, const float* __restrict__ bk,
                       const float* __restrict__ wv, const float* __restrict__ bv,
                       f16* __restrict__ wh, float* __restrict__ bcat) {
  int o = blockIdx.x;          // 512 rows: 0-127 q, 128-255 k, 256-511 v
  int c = threadIdx.x;         // 256
  const float* wrow; float bias;
  if (o < 128)      { wrow = wq + (size_t)o * 256;         bias = bq[o]; }
  else if (o < 256) { wrow = wk + (size_t)(o - 128) * 256; bias = bk[o - 128]; }
  else              { wrow = wv + (size_t)(o - 256) * 256; bias = bv[o - 256]; }
  wh[(size_t)(o >> 4) * 4096 + (size_t)(c >> 5) * 512 +
     (size_t)((c >> 3) & 3) * 128 + (o & 15) * 8 + (c & 7)] = (f16)wrow[c];
  if (c == 0) bcat[o] = bias;
}

// ---------------- kernel 0b: x transpose -> fragment-tiled f16 ----------------
// xTf elem (t,c): b*1048576 + (t>>4)*4096 + (c>>5)*512 + ((c>>3)&3)*128
//                 + (t&15)*8 + (c&7)
__global__ void k_xsplit(const float* __restrict__ x, f16* __restrict__ xh) {
  __shared__ float t[64][65];
  int b = blockIdx.z, c0 = blockIdx.y * 64, n0 = blockIdx.x * 64;
  int tx = threadIdx.x & 63, ty = threadIdx.x >> 6;
  const float* xb = x + ((size_t)b * 256 + c0) * 4096 + n0;
#pragma unroll
  for (int r = ty; r < 64; r += 4) t[r][tx] = xb[(size_t)r * 4096 + tx];
  __syncthreads();
  f16* xbb = xh + (size_t)b * 1048576;
#pragma unroll
  for (int k2 = 0; k2 < 2; k2++) {
    int id = k2 * 256 + threadIdx.x;
    int tok = id & 63, oct = id >> 6;          // oct = 8-channel group 0..7
    int tt = n0 + tok;
    f16x8v v;
#pragma unroll
    for (int e = 0; e < 8; e++) v[e] = (f16)t[oct * 8 + e][tok];
    size_t addr = (size_t)(tt >> 4) * 4096 +
                  (size_t)((c0 >> 5) + (oct >> 2)) * 512 +
                  (size_t)(oct & 3) * 128 + (tt & 15) * 8;
    *(f16x8v*)&xbb[addr] = v;
  }
}

// ---------------- kernel 1: projections, register-direct (k_rows pattern) ----------------
// wg = (ob 0..7: 64 o, th 0..7: 512 tokens, b). 512 thr. Wave (tt=w&3,
// oh=w>>2): holds TWO W o-tiles resident (wb[2][8], 64 VGPR); loops 8 iters
// of token-tile T = th*32 + it*4 + tt, A-frags dbuf reg-prefetched; 16 MFMA
// per 8 A-loads; per-iter epilogue writes qT/kT/vT (layouts unchanged).
// No LDS, no barriers.
//  qT/kT elem (i,d): b*524288 + (i>>4)*2048 + (d>>5)*512 + ((d>>3)&3)*128
//                    + (i&15)*8 + (d&7)
//  vT   elem (c,i): b*1048576 + (c>>4)*65536 + (i>>5)*512 + ((i>>3)&3)*128
//                    + (c&15)*8 + (i&7)
__global__ void __launch_bounds__(512, 1)
k_proj(const f16* __restrict__ xh, const f16* __restrict__ wh,
       const float* __restrict__ bcat, f16* __restrict__ qT,
       f16* __restrict__ kT, f16* __restrict__ vT) {
  int ob = blockIdx.x, th = blockIdx.y, b = blockIdx.z;
  int tid = threadIdx.x, l = tid & 63, w = tid >> 6;
  int col = l & 15, quad = l >> 4;
  int tt = w & 3, oh = w >> 2;
  int OT0 = ob * 4 + oh * 2;                   // first of 2 resident o-tiles
  const f16* wtb = wh + (size_t)OT0 * 4096 + l * 8;
  f16x8v wb[2][8];
#pragma unroll
  for (int jt = 0; jt < 2; jt++)
#pragma unroll
    for (int ks = 0; ks < 8; ks++)
      wb[jt][ks] = *(const f16x8v*)(wtb + jt * 4096 + ks * 512);
  float bias0 = bcat[OT0 * 16 + col];
  float bias1 = bcat[OT0 * 16 + 16 + col];
  const f16* atb = xh + (size_t)b * 1048576 + (size_t)(th * 32 + tt) * 4096 + l * 8;
  f16x8v afA[8], afB[8];
#pragma unroll
  for (int ks = 0; ks < 8; ks++) afA[ks] = *(const f16x8v*)(atb + ks * 512);

#define PROJ_BODY(IT, AF, AN, PREF)                                            \
  {                                                                            \
    if (PREF) {                                                                \
      _Pragma("unroll") for (int ks = 0; ks < 8; ks++)                         \
        AN[ks] = *(const f16x8v*)(atb + (size_t)((IT) + 1) * 16384 + ks * 512);\
    }                                                                          \
    f32x4v s0 = {}, s1 = {};                                                   \
    _Pragma("unroll") for (int ks = 0; ks < 8; ks++) {                         \
      s0 = mfma16(AF[ks], wb[0][ks], s0);                                      \
      s1 = mfma16(AF[ks], wb[1][ks], s1);                                      \
    }                                                                          \
    int T = th * 32 + (IT) * 4 + tt;                                           \
    if (ob < 4) {                                                              \
      f16* dst = (ob < 2) ? qT : kT;                                           \
      _Pragma("unroll") for (int jt = 0; jt < 2; jt++) {                       \
        int o = OT0 * 16 + jt * 16 + col;                                      \
        int d = o & 127;                                                       \
        float bs = jt ? bias1 : bias0;                                         \
        size_t base = (size_t)b * 524288 + (size_t)T * 2048 +                  \
                      (size_t)(d >> 5) * 512 + (size_t)((d >> 3) & 3) * 128 +  \
                      (d & 7);                                                 \
        float sv0 = jt ? s1[0] : s0[0], sv1 = jt ? s1[1] : s0[1];              \
        float sv2 = jt ? s1[2] : s0[2], sv3 = jt ? s1[3] : s0[3];              \
        dst[base + (quad * 4 + 0) * 8] = (f16)(sv0 + bs);                      \
        dst[base + (quad * 4 + 1) * 8] = (f16)(sv1 + bs);                      \
        dst[base + (quad * 4 + 2) * 8] = (f16)(sv2 + bs);                      \
        dst[base + (quad * 4 + 3) * 8] = (f16)(sv3 + bs);                      \
      }                                                                        \
    } else {                                                                   \
      int i0 = T * 16 + quad * 4;                                              \
      size_t ibase = (size_t)b * 1048576 + (size_t)(i0 >> 5) * 512 +           \
                     (size_t)((i0 >> 3) & 3) * 128 + (i0 & 7);                 \
      _Pragma("unroll") for (int jt = 0; jt < 2; jt++) {                       \
        int c = OT0 * 16 + jt * 16 + col - 256;                                \
        float bs = jt ? bias1 : bias0;                                         \
        f16x4v pv;                                                             \
        _Pragma("unroll") for (int rg = 0; rg < 4; rg++)                       \
          pv[rg] = (f16)((jt ? s1[rg] : s0[rg]) + bs);                         \
        *(f16x4v*)&vT[ibase + (size_t)(c >> 4) * 65536 + (c & 15) * 8] = pv;   \
      }                                                                        \
    }                                                                          \
  }

  for (int itp = 0; itp < 4; itp++) {
    int itA = itp * 2;
    PROJ_BODY(itA, afA, afB, true)
    PROJ_BODY(itA + 1, afB, afA, itp < 3)
  }
#undef PROJ_BODY
}

// ---------------- kernel 2: row sums of exp(S), widened (128 j per wg) ----------------
// wg = (jblk [0,32), ih [0,2), b), 512 thr. Wave (ti=w&3, jh=w>>2): holds
// FOUR K j-tiles resident; 32 i-iters, Q frags dbuf-prefetched; 16 MFMA per
// 4 Q-loads. partial[b][jblk*2+jh][i] = sum over 64 j of exp. No LDS/barriers.
__global__ void __launch_bounds__(512, 2)
k_rows(const f16* __restrict__ qT, const f16* __restrict__ kT,
       float* __restrict__ partial) {
  int jblk = blockIdx.x, ih = blockIdx.y, b = blockIdx.z;
  int tid = threadIdx.x, l = tid & 63, w = tid >> 6;
  int col = l & 15;
  int ti = w & 3, jh = w >> 2;
  const f16* ktb = kT + (size_t)b * 524288 + (size_t)(jblk * 8 + jh * 4) * 2048 + l * 8;
  const f16* qtb = qT + (size_t)b * 524288 + (size_t)ti * 2048 + l * 8;
  f16x8v ka[4][4];
#pragma unroll
  for (int jt = 0; jt < 4; jt++)
#pragma unroll
    for (int ks = 0; ks < 4; ks++)
      ka[jt][ks] = *(const f16x8v*)(ktb + jt * 2048 + ks * 512);
  float* pout = partial + ((size_t)(b * 32 + jblk) * 2 + jh) * 4096 + ti * 16 + col;
  int it0 = ih * 32;
  f16x8v qfA[4], qfB[4];
#pragma unroll
  for (int ks = 0; ks < 4; ks++)
    qfA[ks] = *(const f16x8v*)(qtb + (size_t)it0 * 8192 + ks * 512);

#define ROWS_BODY(IT, QF, QN, PREF)                                           \
  {                                                                           \
    if (PREF) {                                                               \
      _Pragma("unroll") for (int ks = 0; ks < 4; ks++)                        \
        QN[ks] = *(const f16x8v*)(qtb + (size_t)((IT) + 1) * 8192 + ks * 512);\
    }                                                                         \
    f32x4v s[4] = {};                                                         \
    _Pragma("unroll") for (int ks = 0; ks < 4; ks++) {                        \
      s[0] = mfma16(ka[0][ks], QF[ks], s[0]);                                 \
      s[1] = mfma16(ka[1][ks], QF[ks], s[1]);                                 \
      s[2] = mfma16(ka[2][ks], QF[ks], s[2]);                                 \
      s[3] = mfma16(ka[3][ks], QF[ks], s[3]);                                 \
    }                                                                         \
    float t = 0.f;                                                            \
    _Pragma("unroll") for (int jt = 0; jt < 4; jt++)                          \
      _Pragma("unroll") for (int rg = 0; rg < 4; rg++)                        \
        t += __expf(s[jt][rg]);                                               \
    t += __shfl_xor(t, 16);                                                   \
    t += __shfl_xor(t, 32);                                                   \
    if (l < 16) pout[(size_t)(IT) * 64] = t;                                  \
  }

  for (int itp = 0; itp < 16; itp++) {
    int itA = it0 + itp * 2;
    ROWS_BODY(itA, qfA, qfB, true)
    ROWS_BODY(itA + 1, qfB, qfA, itp < 15)
  }
#undef ROWS_BODY
}

// ---------------- kernel 3: combine partials -> rinv = 1/rowsum ----------------
__global__ void k_rsum(const float* __restrict__ partial, float* __restrict__ rinv) {
  int b = blockIdx.y;
  int i = blockIdx.x * 256 + threadIdx.x;
  const float* p = partial + (size_t)b * 64 * 4096 + i;
  float s = 0.f;
#pragma unroll 8
  for (int jb = 0; jb < 64; jb++) s += p[(size_t)jb * 4096];
  rinv[(size_t)b * 4096 + i] = 1.0f / s;
}

// ---------------- kernel 4: fused recompute + AV, register-direct tiled ----------------
// BYTE-IDENTICAL to the R4/R15 kernel that measured 62.2us and passed 3x.
__global__ void __launch_bounds__(512, 2)
k_fav(const f16* __restrict__ qT, const f16* __restrict__ kT,
      const f16* __restrict__ vT, const float* __restrict__ rinv,
      const float* __restrict__ x, const float* __restrict__ gamma,
      float* __restrict__ out) {
  __shared__ f16 sE[2][4096];   // [buf][64 j][64 i], 8-elem i-groups XOR(j&7)
  // XCD-chunked swizzle: 256 wgs, 8 XCDs -> contiguous 32-wg slice per XCD.
  int wg = blockIdx.x;
  int lg = (wg & 7) * 32 + (wg >> 3);
  int b = lg >> 6, j0 = (lg & 63) * 64;
  int tid = threadIdx.x, l = tid & 63, w = tid >> 6;
  int col = l & 15, quad = l >> 4;
  int ti = w & 3, tjb = (w >> 2) * 2;
  const f16* ktb = kT + (size_t)b * 524288 + (size_t)(j0 / 16 + tjb) * 2048 + l * 8;
  const f16* qtb = qT + (size_t)b * 524288 + (size_t)ti * 2048 + l * 8;
  const f16* vtb = vT + (size_t)b * 1048576 + (size_t)(w * 2) * 65536 + l * 8;
  const float* rp = rinv + (size_t)b * 4096 + ti * 16 + col;
  // K fragments: resident whole kernel
  f16x8v ka0[4], ka1[4];
#pragma unroll
  for (int ks = 0; ks < 4; ks++) {
    ka0[ks] = *(const f16x8v*)(ktb + ks * 512);
    ka1[ks] = *(const f16x8v*)(ktb + 2048 + ks * 512);
  }
  f16x8v qfA[4], qfB[4], vfA[2][2], vfB[2][2];
  float rvA, rvB;
#pragma unroll
  for (int ks = 0; ks < 4; ks++) qfA[ks] = *(const f16x8v*)(qtb + ks * 512);
#pragma unroll
  for (int mt = 0; mt < 2; mt++)
#pragma unroll
    for (int ks = 0; ks < 2; ks++)
      vfA[mt][ks] = *(const f16x8v*)(vtb + mt * 65536 + ks * 512);
  rvA = rp[0];
  f32x4v acc[2][4] = {};
  int ig = ti * 2 + (col >> 3);
  int i_lo = col & 7;

#define FAV_BODY(IT, QF, VF, RV, QN, VN, RN, PREF, SEB)                        \
  {                                                                            \
    if (PREF) {                                                                \
      _Pragma("unroll") for (int ks = 0; ks < 4; ks++)                         \
        QN[ks] = *(const f16x8v*)(qtb + (size_t)((IT) + 1) * 8192 + ks * 512); \
      _Pragma("unroll") for (int mt = 0; mt < 2; mt++)                         \
        _Pragma("unroll") for (int ks = 0; ks < 2; ks++)                       \
          VN[mt][ks] = *(const f16x8v*)(vtb + mt * 65536 +                     \
                                        (size_t)(((IT) + 1) * 2 + ks) * 512);  \
      RN = rp[((IT) + 1) * 64];                                                \
    }                                                                          \
    f32x4v s0 = {}, s1 = {};                                                   \
    _Pragma("unroll") for (int ks = 0; ks < 4; ks++) {                         \
      s0 = mfma16(ka0[ks], QF[ks], s0);                                        \
      s1 = mfma16(ka1[ks], QF[ks], s1);                                        \
    }                                                                          \
    _Pragma("unroll") for (int rg = 0; rg < 4; rg++) {                         \
      int jl0 = tjb * 16 + quad * 4 + rg;                                      \
      sE[SEB][jl0 * 64 + ((ig ^ (jl0 & 7)) * 8) + i_lo] = (f16)(__expf(s0[rg]) * RV); \
      sE[SEB][(jl0 + 16) * 64 + ((ig ^ (jl0 & 7)) * 8) + i_lo] = (f16)(__expf(s1[rg]) * RV); \
    }                                                                          \
    asm volatile("s_waitcnt lgkmcnt(0)\n\ts_barrier" ::: "memory");            \
    _Pragma("unroll") for (int ks = 0; ks < 2; ks++) {                         \
      int sw = ((ks * 4 + quad) ^ (col & 7)) * 8;                              \
      f16x8v e0 = *(const f16x8v*)&sE[SEB][col * 64 + sw];                     \
      f16x8v e1 = *(const f16x8v*)&sE[SEB][(16 + col) * 64 + sw];              \
      f16x8v e2 = *(const f16x8v*)&sE[SEB][(32 + col) * 64 + sw];              \
      f16x8v e3 = *(const f16x8v*)&sE[SEB][(48 + col) * 64 + sw];              \
      acc[0][0] = mfma16(VF[0][ks], e0, acc[0][0]);                            \
      acc[0][1] = mfma16(VF[0][ks], e1, acc[0][1]);                            \
      acc[0][2] = mfma16(VF[0][ks], e2, acc[0][2]);                            \
      acc[0][3] = mfma16(VF[0][ks], e3, acc[0][3]);                            \
      acc[1][0] = mfma16(VF[1][ks], e0, acc[1][0]);                            \
      acc[1][1] = mfma16(VF[1][ks], e1, acc[1][1]);                            \
      acc[1][2] = mfma16(VF[1][ks], e2, acc[1][2]);                            \
      acc[1][3] = mfma16(VF[1][ks], e3, acc[1][3]);                            \
    }                                                                          \
  }

  for (int itp = 0; itp < 32; itp++) {
    int itA = itp * 2;
    FAV_BODY(itA, qfA, vfA, rvA, qfB, vfB, rvB, true, 0)
    FAV_BODY(itA + 1, qfB, vfB, rvB, qfA, vfA, rvA, itp < 31, 1)
  }
#undef FAV_BODY

  float gm = gamma[0];
  const float* xb = x + (size_t)b * 256 * 4096;
  float* ob = out + (size_t)b * 256 * 4096;
#pragma unroll
  for (int mt = 0; mt < 2; mt++)
#pragma unroll
    for (int jt = 0; jt < 4; jt++) {
      int c = w * 32 + mt * 16 + quad * 4;
      int j = j0 + jt * 16 + col;
#pragma unroll
      for (int rg = 0; rg < 4; rg++) {
        size_t off = (size_t)(c + rg) * 4096 + j;
        ob[off] = gm * acc[mt][jt][rg] + xb[off];
      }
    }
}

extern "C" void kernel_launch(void* const* d_in, const int* in_sizes, int n_in,
                              void* d_out, int out_size, void* d_ws, size_t ws_size,
                              hipStream_t stream) {
  (void)in_sizes; (void)n_in; (void)out_size; (void)ws_size;
  const float* x  = (const float*)d_in[0];
  const float* wq = (const float*)d_in[1];
  const float* bq = (const float*)d_in[2];
  const float* wk = (const float*)d_in[3];
  const float* bk = (const float*)d_in[4];
  const float* wv = (const float*)d_in[5];
  const float* bv = (const float*)d_in[6];
  const float* gm = (const float*)d_in[7];
  float* out = (float*)d_out;

  char* ws = (char*)d_ws;
  f16*  xh = (f16*)ws;                          // 8 MB fragment-tiled x
  f16*  qT = (f16*)(ws + 8388608);              // 4 MB fragment-tiled Q
  f16*  kT = (f16*)(ws + 12582912);             // 4 MB fragment-tiled K
  f16*  vT = (f16*)(ws + 16777216);             // 8 MB fragment-tiled V
  f16*  wh = (f16*)(ws + 25165824);             // 256 KB fragment-tiled W
  float* bcat    = (float*)(ws + 25427968);     // 2 KB
  float* rinv    = (float*)(ws + 25430016);     // 64 KB
  float* partial = (float*)(ws + 25495552);     // 4 MB: [b][64][4096]

  hipLaunchKernelGGL(k_wcvt, dim3(512), dim3(256), 0, stream, wq, bq, wk, bk, wv, bv, wh, bcat);
  hipLaunchKernelGGL(k_xsplit, dim3(64, 4, 4), dim3(256), 0, stream, x, xh);
  hipLaunchKernelGGL(k_proj, dim3(8, 8, 4), dim3(512), 0, stream, xh, wh, bcat, qT, kT, vT);
  hipLaunchKernelGGL(k_rows, dim3(32, 2, 4), dim3(512), 0, stream, qT, kT, partial);
  hipLaunchKernelGGL(k_rsum, dim3(16, 4), dim3(256), 0, stream, partial, rinv);
  hipLaunchKernelGGL(k_fav, dim3(256), dim3(512), 0, stream, qT, kT, vT, rinv, x, gm, out);
}